// Round 2
// baseline (93111.823 us; speedup 1.0000x reference)
//
#include <hip/hip_runtime.h>
#include <cstdint>

// ---------------- problem constants ----------------
#define SEQ   512
#define BATCH 64
#define HID   512
#define NWG   8      // workgroups per pool (layer)
#define NTHR  512    // threads per WG = 8 waves

#define MOG_ELEMS   (5*512*512)                  // 1310720
#define GATE_ELEMS  (2048*512)                   // 1048576
#define LAYER_ELEMS (MOG_ELEMS + 2*GATE_ELEMS)   // 3407872

// ---------------- ws layout (bytes) ----------------
#define WS_CNT  0            // 2 pools * 512 t * 6 phases * 4B = 24576
#define WS_H16  24576        // 2 pools * 2 bufs * 64*512 * 2B = 262144
#define ZERO_PREFIX 286720   // cnt + h16 zeroed each launch
#define WS_X16  286720       // 2 pools * 64*512 * 2B = 131072
#define WS_RING 417792       // 4 slots * 64*512 * 4B = 524288 (h1 ring A->B, f32)
#define WS_WT   942080       // 2 layers * LAYER_ELEMS * 2B = 13631488 (end 14573568)

// d_out layout (floats)
#define OUT_H 16777216       // last_hidden [2,64,512]
#define OUT_C 16842752       // last_cell   [2,64,512]

typedef _Float16 f16x8 __attribute__((ext_vector_type(8)));
typedef float    f32x4 __attribute__((ext_vector_type(4)));

#define MFMA(a,b,c) __builtin_amdgcn_mfma_f32_16x16x32_f16((a),(b),(c),0,0,0)

// Reordered gate layout: rg = 64*b + 16*gate + j  <->  orig row = gate*512 + 16*b + j
__device__ __forceinline__ int gate_orig_row(int rg) {
    return ((rg >> 4) & 3) * 512 + ((rg >> 6) << 4) + (rg & 15);
}

// ---------------- prologue: f32 -> f16 weight conversion + gate reorder ----------------
__global__ __launch_bounds__(256)
void prologue_convert(const float* __restrict__ l1_mogW, const float* __restrict__ l1_Wih,
                      const float* __restrict__ l1_Whh,
                      const float* __restrict__ l2_mogW, const float* __restrict__ l2_Wih,
                      const float* __restrict__ l2_Whh,  char* __restrict__ ws)
{
    _Float16* wdst = (_Float16*)(ws + WS_WT);
    const int total = 2 * LAYER_ELEMS;
    const int stride = gridDim.x * blockDim.x;
    for (int idx = blockIdx.x * blockDim.x + threadIdx.x; idx < total; idx += stride) {
        const int layer = idx >= LAYER_ELEMS;
        const int r = idx - layer * LAYER_ELEMS;
        float v;
        if (r < MOG_ELEMS) {
            v = (layer ? l2_mogW : l1_mogW)[r];
        } else {
            const int q = r - MOG_ELEMS;
            const int mat = q >= GATE_ELEMS;          // 0 = Wih, 1 = Whh
            const int e = q - mat * GATE_ELEMS;
            const int rg = e >> 9;
            const int k  = e & 511;
            const int orig = gate_orig_row(rg);
            const float* W = mat ? (layer ? l2_Whh : l1_Whh)
                                 : (layer ? l2_Wih : l1_Wih);
            v = W[orig * 512 + k];
        }
        wdst[idx] = (_Float16)v;
    }
}

// ---------------- uncached (coherence-point) accessors ----------------
// Relaxed agent-scope atomics compile to sc0/sc1 loads/stores: they bypass the
// non-coherent per-XCD caches WITHOUT emitting cache-wide buffer_inv/buffer_wbl2.
__device__ __forceinline__ f16x8 ld_f16x8_uc(const _Float16* p) {
    union { unsigned long long q[2]; f16x8 v; } u;
    u.q[0] = __hip_atomic_load((const unsigned long long*)p,       __ATOMIC_RELAXED, __HIP_MEMORY_SCOPE_AGENT);
    u.q[1] = __hip_atomic_load((const unsigned long long*)(p + 4), __ATOMIC_RELAXED, __HIP_MEMORY_SCOPE_AGENT);
    return u.v;
}
__device__ __forceinline__ float ld_f32_uc(const float* p) {
    unsigned b = __hip_atomic_load((const unsigned*)p, __ATOMIC_RELAXED, __HIP_MEMORY_SCOPE_AGENT);
    return __builtin_bit_cast(float, b);
}
__device__ __forceinline__ void st_f16_uc(_Float16* p, _Float16 v) {
    __hip_atomic_store((unsigned short*)p, __builtin_bit_cast(unsigned short, v),
                       __ATOMIC_RELAXED, __HIP_MEMORY_SCOPE_AGENT);
}
__device__ __forceinline__ void st_f32_uc(float* p, float v) {
    __hip_atomic_store((unsigned*)p, __builtin_bit_cast(unsigned, v),
                       __ATOMIC_RELAXED, __HIP_MEMORY_SCOPE_AGENT);
}

// ---------------- sync primitives ----------------
// wait: RELAXED poll (no buffer_inv!). Safe because all cross-WG-mutable data is
// read via uncached (sc0/sc1) atomic loads; cached data is read-only.
__device__ __forceinline__ void wg_wait(const unsigned* c, unsigned target) {
    if (threadIdx.x == 0) {
        while (__hip_atomic_load(c, __ATOMIC_RELAXED, __HIP_MEMORY_SCOPE_AGENT) < target) { }
    }
    __syncthreads();
    asm volatile("" ::: "memory");
}
// signal: __syncthreads drains every wave's vmcnt (sc1 store acks = visible at
// coherence point); RELEASE add writes back any cached dirty lines once.
__device__ __forceinline__ void wg_signal(unsigned* c) {
    __syncthreads();
    if (threadIdx.x == 0) {
        __hip_atomic_fetch_add(c, 1u, __ATOMIC_RELEASE, __HIP_MEMORY_SCOPE_AGENT);
    }
}

__device__ __forceinline__ float sigf(float z) { return 1.f / (1.f + __expf(-z)); }

// ---------------- persistent kernel ----------------
// grid = 16 blocks x 512 threads. Pool 0 (blocks 0..7) = layer 1, pool 1 = layer 2.
// Per WG: 64-col slice. Per wave (8): row-tile rt = wv&3, col-tiles {b0, b0+2}, b0 = wv>>2.
// MFMA 16x16x32 f16: A row = lane&15, k = (lane>>4)*8+j ; C/D col = lane&15, row=(lane>>4)*4+reg.
// All recurrent f32 state (x, h, c) lives in registers with a fixed thread<->cell map;
// only f16 broadcast copies (x16, h16) + f32 ring cross WG boundaries (uncached).
__global__ __launch_bounds__(NTHR)
void moglstm_persist(const float* __restrict__ in_seq,
                     const float* __restrict__ mogb1, const float* __restrict__ mogb2,
                     const float* __restrict__ bih1,  const float* __restrict__ bhh1,
                     const float* __restrict__ bih2,  const float* __restrict__ bhh2,
                     float* __restrict__ out, char* __restrict__ ws)
{
    const int pool = blockIdx.x >> 3;
    const int w    = blockIdx.x & 7;
    const int tid  = threadIdx.x;
    const int lane = tid & 63;
    const int wv   = tid >> 6;

    unsigned* cnt  = (unsigned*)(ws + WS_CNT);
    unsigned* cntA = cnt;
    unsigned* cntB = cnt + SEQ * 6;
    unsigned* cntP = cnt + pool * SEQ * 6;

    _Float16* h16 = (_Float16*)(ws + WS_H16) + pool * (2 * BATCH * HID);
    _Float16* x16 = (_Float16*)(ws + WS_X16) + pool * (BATCH * HID);
    float*    ring = (float*)(ws + WS_RING);
    const _Float16* Wb   = (const _Float16*)(ws + WS_WT) + pool * LAYER_ELEMS;
    const _Float16* mogW = Wb;
    const _Float16* wihR = Wb + MOG_ELEMS;
    const _Float16* whhR = wihR + GATE_ELEMS;
    const float* mogb = pool ? mogb2 : mogb1;
    const float* bih  = pool ? bih2 : bih1;
    const float* bhh  = pool ? bhh2 : bhh1;

    const int rt  = wv & 3;
    const int b0  = wv >> 2;            // col-tile tasks b0 and b0+2
    const int j   = lane & 15;
    const int hi  = lane >> 4;
    const int kof = hi * 8;
    const int arow  = 16 * rt + j;      // A-fragment row
    const int erow0 = 16 * rt + hi * 4; // C/D row base
    const int col0  = 64 * w + 16 * b0 + j;
    const int col1  = 64 * w + 16 * (b0 + 2) + j;

    // hoist all biases into registers (constant over t)
    float mb[5][2];
    #pragma unroll
    for (int p = 0; p < 5; ++p) { mb[p][0] = mogb[p*512 + col0]; mb[p][1] = mogb[p*512 + col1]; }
    float gb[2][4];
    #pragma unroll
    for (int q = 0; q < 2; ++q) {
        const int hc = q ? col1 : col0;
        #pragma unroll
        for (int g = 0; g < 4; ++g) gb[q][g] = bih[g*512 + hc] + bhh[g*512 + hc];
    }

    float xreg[2][4];
    float hreg[2][4] = {};
    float creg[2][4] = {};

    for (int t = 0; t < SEQ; ++t) {
        _Float16* hb = h16 + (t & 1) * (BATCH * HID);
        _Float16* ho = h16 + ((t & 1) ^ 1) * (BATCH * HID);

        // ---------------- mogrifier phases 0..4 (fully unrolled) ----------------
        #pragma unroll
        for (int p = 0; p < 5; ++p) {
            if (p == 0) {
                if (t > 0) wg_wait(&cntP[(t - 1) * 6 + 5], NWG);
                if (pool == 1) wg_wait(&cntA[t * 6 + 5], NWG);
            } else {
                wg_wait(&cntP[t * 6 + p - 1], NWG);
            }

            const _Float16* act = (p & 1) ? x16 : hb;   // even: h input; odd: x input
            const _Float16* Wp  = mogW + p * (512 * 512);
            const _Float16* ap  = act + arow * 512 + kof;
            const _Float16* bp0 = Wp + (size_t)col0 * 512 + kof;
            const _Float16* bp1 = Wp + (size_t)col1 * 512 + kof;
            f32x4 acc0 = {0.f,0.f,0.f,0.f}, acc1 = {0.f,0.f,0.f,0.f};
            #pragma unroll
            for (int ks = 0; ks < 16; ++ks) {
                const int o = ks * 32;
                f16x8 a  = ld_f16x8_uc(ap + o);
                f16x8 w0 = *(const f16x8*)(bp0 + o);
                f16x8 w1 = *(const f16x8*)(bp1 + o);
                acc0 = MFMA(a, w0, acc0);
                acc1 = MFMA(a, w1, acc1);
            }
            #pragma unroll
            for (int q = 0; q < 2; ++q) {
                const f32x4 acv = q ? acc1 : acc0;
                const int col = q ? col1 : col0;
                #pragma unroll
                for (int r = 0; r < 4; ++r) {
                    const int row = erow0 + r;
                    const float s = 2.f * sigf(acv[r] + mb[p][q]);
                    if ((p & 1) == 0) {
                        float xo;
                        if (p == 0) {
                            xo = (pool == 0)
                               ? in_seq[t * (BATCH * HID) + row * HID + col]
                               : ld_f32_uc(&ring[(t & 3) * (BATCH * HID) + row * HID + col]);
                        } else {
                            xo = xreg[q][r];
                        }
                        const float xn = s * xo;
                        xreg[q][r] = xn;
                        st_f16_uc(&x16[row * HID + col], (_Float16)xn);
                    } else {
                        const float hn = s * hreg[q][r];
                        hreg[q][r] = hn;
                        st_f16_uc(&hb[row * HID + col], (_Float16)hn);
                    }
                }
            }
            wg_signal(&cntP[t * 6 + p]);
        }

        // ---------------- LSTM gates ----------------
        wg_wait(&cntP[t * 6 + 4], NWG);
        if (pool == 0 && t >= 4) wg_wait(&cntB[(t - 4) * 6 + 0], NWG);  // ring slot free

        f32x4 acc[2][4] = {};
        {
            const _Float16* xa = x16 + arow * 512 + kof;
            const _Float16* ha = hb  + arow * 512 + kof;
            const size_t rg0 = (size_t)(256 * w + 64 * b0 + j) * 512 + kof;
            const size_t rg1 = (size_t)(256 * w + 64 * (b0 + 2) + j) * 512 + kof;
            const _Float16* bi0 = wihR + rg0;  const _Float16* bh0 = whhR + rg0;
            const _Float16* bi1 = wihR + rg1;  const _Float16* bh1 = whhR + rg1;
            #pragma unroll
            for (int ks = 0; ks < 16; ++ks) {
                const int o = ks * 32;
                f16x8 ax = ld_f16x8_uc(xa + o);
                f16x8 ah = ld_f16x8_uc(ha + o);
                #pragma unroll
                for (int g = 0; g < 4; ++g) {
                    acc[0][g] = MFMA(ax, *(const f16x8*)(bi0 + g * 8192 + o), acc[0][g]);
                    acc[0][g] = MFMA(ah, *(const f16x8*)(bh0 + g * 8192 + o), acc[0][g]);
                    acc[1][g] = MFMA(ax, *(const f16x8*)(bi1 + g * 8192 + o), acc[1][g]);
                    acc[1][g] = MFMA(ah, *(const f16x8*)(bh1 + g * 8192 + o), acc[1][g]);
                }
            }
        }
        #pragma unroll
        for (int q = 0; q < 2; ++q) {
            const int hc = q ? col1 : col0;
            #pragma unroll
            for (int r = 0; r < 4; ++r) {
                const int row = erow0 + r;
                const float ig = sigf (acc[q][0][r] + gb[q][0]);
                const float fg = sigf (acc[q][1][r] + gb[q][1]);
                const float gg = tanhf(acc[q][2][r] + gb[q][2]);
                const float og = sigf (acc[q][3][r] + gb[q][3]);
                const float cn = fg * creg[q][r] + ig * gg;
                creg[q][r] = cn;
                const float hn = og * tanhf(cn);
                hreg[q][r] = hn;
                st_f16_uc(&ho[row * HID + hc], (_Float16)hn);
                if (pool == 0) {
                    st_f32_uc(&ring[(t & 3) * (BATCH * HID) + row * HID + hc], hn);
                } else {
                    out[t * (BATCH * HID) + row * HID + hc] = hn;
                }
                if (t == SEQ - 1) {
                    out[OUT_H + pool * (BATCH * HID) + row * HID + hc] = hn;
                    out[OUT_C + pool * (BATCH * HID) + row * HID + hc] = cn;
                }
            }
        }
        wg_signal(&cntP[t * 6 + 5]);
    }
}

// ---------------- host launch ----------------
extern "C" void kernel_launch(void* const* d_in, const int* in_sizes, int n_in,
                              void* d_out, int out_size, void* d_ws, size_t ws_size,
                              hipStream_t stream) {
    const float* in_seq  = (const float*)d_in[0];
    const float* l1_mogW = (const float*)d_in[1];
    const float* l1_mogb = (const float*)d_in[2];
    const float* l1_Wih  = (const float*)d_in[3];
    const float* l1_Whh  = (const float*)d_in[4];
    const float* l1_bih  = (const float*)d_in[5];
    const float* l1_bhh  = (const float*)d_in[6];
    const float* l2_mogW = (const float*)d_in[7];
    const float* l2_mogb = (const float*)d_in[8];
    const float* l2_Wih  = (const float*)d_in[9];
    const float* l2_Whh  = (const float*)d_in[10];
    const float* l2_bih  = (const float*)d_in[11];
    const float* l2_bhh  = (const float*)d_in[12];

    hipMemsetAsync(d_ws, 0, ZERO_PREFIX, stream);

    prologue_convert<<<256, 256, 0, stream>>>(l1_mogW, l1_Wih, l1_Whh,
                                              l2_mogW, l2_Wih, l2_Whh, (char*)d_ws);

    moglstm_persist<<<16, NTHR, 0, stream>>>(in_seq, l1_mogb, l2_mogb,
                                             l1_bih, l1_bhh, l2_bih, l2_bhh,
                                             (float*)d_out, (char*)d_ws);
}

// Round 4
// 87708.502 us; speedup vs baseline: 1.0616x; 1.0616x over previous
//
#include <hip/hip_runtime.h>
#include <cstdint>

// ---------------- problem constants ----------------
#define SEQ   512
#define BATCH 64
#define HID   512
#define BH    (BATCH*HID)          // 32768
#define NWG   8                    // workgroups per pool
#define NTHR  512                  // 8 waves

#define MOG_ELEMS   (5*512*512)                  // 1310720
#define GATE_ELEMS  (2048*512)                   // 1048576
#define LAYER_ELEMS (MOG_ELEMS + 2*GATE_ELEMS)   // 3407872

// ---------------- ws layout (bytes) ----------------
#define WS_CNT0  0          // pool0 counters 512*6*4 = 12288
#define WS_CNT1  12288      // pool1 counters
#define WS_IAB   24576      // iab[512]: pool0 gates(t) done -> pool1 p0(t)
#define WS_IBA   26624      // iba[512]: pool1 p0(t) done  -> ring slot t free
#define WS_H16   28672      // 2 pools * 2 bufs * BH * 2B = 262144
#define ZERO_PREFIX 290816  // everything above zeroed each launch
#define WS_X16   290816     // 2 pools * BH * 2B = 131072
#define WS_RING  421888     // 4 slots * BH * 4B = 524288 (h1 f32, pool0->pool1)
#define WS_WT    946176     // 2 layers * LAYER_ELEMS * 2B = 13631488 (end 14577664)

// d_out layout (floats)
#define OUT_H 16777216
#define OUT_C 16842752

typedef _Float16 f16x8 __attribute__((ext_vector_type(8)));
typedef float    f32x4 __attribute__((ext_vector_type(4)));

#define MFMA(a,b,c) __builtin_amdgcn_mfma_f32_16x16x32_f16((a),(b),(c),0,0,0)

// ---------------- batched IC-coherent access ----------------
// Plain (non-atomic) loads/stores with sc0 sc1: bypass non-coherent L1/L2, served
// by the device coherence point. Coalesce like normal vector ops; ONE vmcnt(0)
// per batch. TIE (register-tie, rule #18) stops hipcc hoisting register-only
// MFMA above the waitcnt.
#define GLD16(dst, base, off) \
    asm volatile("global_load_dwordx4 %0, %1, off offset:%c2 sc0 sc1" \
                 : "=v"(dst) : "v"(base), "i"(off))
#define GLDF(dst, addr) \
    asm volatile("global_load_dword %0, %1, off sc0 sc1" : "=v"(dst) : "v"(addr))
#define VMWAIT() asm volatile("s_waitcnt vmcnt(0)" ::: "memory")
#define TIE(x)   asm volatile("" : "+v"(x))

__device__ __forceinline__ void st_h16(_Float16* p, _Float16 v) {
    unsigned b = (unsigned)__builtin_bit_cast(unsigned short, v);
    asm volatile("global_store_short %0, %1, off sc0 sc1" :: "v"(p), "v"(b) : "memory");
}
__device__ __forceinline__ void st_f32cc(float* p, float v) {
    asm volatile("global_store_dword %0, %1, off sc0 sc1" :: "v"(p), "v"(v) : "memory");
}

// ---------------- sync primitives (R2-proven; device-scope, no invalidates) ----
__device__ __forceinline__ void wg_wait(unsigned* c, unsigned tgt) {
    if (threadIdx.x == 0) {
        while (__hip_atomic_load(c, __ATOMIC_RELAXED, __HIP_MEMORY_SCOPE_AGENT) < tgt) { }
    }
    __syncthreads();   // broadcast; also drains this wave's outstanding vmem
}
// __syncthreads drains every wave's vmcnt (sc1 store acks = visible at coherence
// point) before tid0 publishes the flag.
__device__ __forceinline__ void wg_signal(unsigned* c) {
    __syncthreads();
    if (threadIdx.x == 0)
        __hip_atomic_fetch_add(c, 1u, __ATOMIC_RELAXED, __HIP_MEMORY_SCOPE_AGENT);
}

__device__ __forceinline__ float sigf(float z) { return 1.f / (1.f + __expf(-z)); }

// Reordered gate layout: rg = 64*b + 16*gate + j  <->  orig row = gate*512 + 16*b + j
__device__ __forceinline__ int gate_orig_row(int rg) {
    return ((rg >> 4) & 3) * 512 + ((rg >> 6) << 4) + (rg & 15);
}

// ---------------- prologue: f32 -> f16 weight conversion + gate reorder --------
__global__ __launch_bounds__(256)
void prologue_convert(const float* __restrict__ l1_mogW, const float* __restrict__ l1_Wih,
                      const float* __restrict__ l1_Whh,
                      const float* __restrict__ l2_mogW, const float* __restrict__ l2_Wih,
                      const float* __restrict__ l2_Whh,  char* __restrict__ ws)
{
    _Float16* wdst = (_Float16*)(ws + WS_WT);
    const int total = 2 * LAYER_ELEMS;
    const int stride = gridDim.x * blockDim.x;
    for (int idx = blockIdx.x * blockDim.x + threadIdx.x; idx < total; idx += stride) {
        const int layer = idx >= LAYER_ELEMS;
        const int r = idx - layer * LAYER_ELEMS;
        float v;
        if (r < MOG_ELEMS) {
            v = (layer ? l2_mogW : l1_mogW)[r];
        } else {
            const int q = r - MOG_ELEMS;
            const int mat = q >= GATE_ELEMS;
            const int e = q - mat * GATE_ELEMS;
            const int rg = e >> 9;
            const int k  = e & 511;
            const int orig = gate_orig_row(rg);
            const float* W = mat ? (layer ? l2_Whh : l1_Whh)
                                 : (layer ? l2_Wih : l1_Wih);
            v = W[orig * 512 + k];
        }
        wdst[idx] = (_Float16)v;
    }
}

// ---------------- persistent kernel ----------------
// grid = 16 x 512. Pool 0 (blocks 0..7) = layer 1, pool 1 = layer 2.
// Per WG: 64 output cols. Per wave: rt = wv&3 (16-row tile), b0 = wv>>2,
// col tiles {b0, b0+2}. Weights cached (preloaded before the flag spin);
// activations via batched sc0sc1 vector ops; flags via agent atomics.
__global__ __launch_bounds__(NTHR)
void moglstm_persist(const float* __restrict__ in_seq,
                     const float* __restrict__ mogb1, const float* __restrict__ mogb2,
                     const float* __restrict__ bih1,  const float* __restrict__ bhh1,
                     const float* __restrict__ bih2,  const float* __restrict__ bhh2,
                     float* __restrict__ out, char* __restrict__ ws)
{
    const int pool = blockIdx.x >> 3;
    const int w    = blockIdx.x & 7;
    const int tid  = threadIdx.x;
    const int lane = tid & 63;
    const int wv   = tid >> 6;

    unsigned* cntP = (unsigned*)(ws + (pool ? WS_CNT1 : WS_CNT0));
    unsigned* iab  = (unsigned*)(ws + WS_IAB);
    unsigned* iba  = (unsigned*)(ws + WS_IBA);

    _Float16* h16  = (_Float16*)(ws + WS_H16) + pool * (2 * BH);
    _Float16* x16  = (_Float16*)(ws + WS_X16) + pool * BH;
    float*    ring = (float*)(ws + WS_RING);
    const _Float16* Wb   = (const _Float16*)(ws + WS_WT) + (size_t)pool * LAYER_ELEMS;
    const _Float16* mogW = Wb;
    const _Float16* wihR = Wb + MOG_ELEMS;
    const _Float16* whhR = wihR + GATE_ELEMS;
    const float* mogb = pool ? mogb2 : mogb1;
    const float* bih  = pool ? bih2 : bih1;
    const float* bhh  = pool ? bhh2 : bhh1;

    const int rt  = wv & 3;
    const int b0  = wv >> 2;
    const int j   = lane & 15;
    const int hi  = lane >> 4;
    const int kof = hi * 8;
    const int arow  = 16 * rt + j;
    const int erow0 = 16 * rt + hi * 4;
    const int col0  = 64 * w + 16 * b0 + j;
    const int col1  = 64 * w + 16 * (b0 + 2) + j;

    // biases hoisted (constant over t)
    float mb[5][2];
    #pragma unroll
    for (int p = 0; p < 5; ++p) { mb[p][0] = mogb[p*512 + col0]; mb[p][1] = mogb[p*512 + col1]; }
    float gb[2][4];
    #pragma unroll
    for (int q = 0; q < 2; ++q) {
        const int hc = q ? col1 : col0;
        #pragma unroll
        for (int g = 0; g < 4; ++g) gb[q][g] = bih[g*512 + hc] + bhh[g*512 + hc];
    }

    float xreg[2][4];
    float hreg[2][4] = {};
    float creg[2][4] = {};

    for (int t = 0; t < SEQ; ++t) {
        _Float16* hb = h16 + (t & 1) * BH;
        _Float16* ho = h16 + ((t & 1) ^ 1) * BH;

        // ---------------- mogrifier phases 0..4 ----------------
        #pragma unroll
        for (int p = 0; p < 5; ++p) {
            const _Float16* act = (p & 1) ? x16 : hb;   // even: h input; odd: x input
            const _Float16* ap  = act + arow * 512 + kof;
            const _Float16* Wp  = mogW + p * (512 * 512);
            const _Float16* bp0 = Wp + (size_t)col0 * 512 + kof;
            const _Float16* bp1 = Wp + (size_t)col1 * 512 + kof;

            // preload col0 weights (cached, flag-independent -> hides under spin)
            f16x8 w0[16];
            #pragma unroll
            for (int ks = 0; ks < 16; ++ks) w0[ks] = *(const f16x8*)(bp0 + ks * 32);

            if (p == 0) {
                if (t > 0) wg_wait(&cntP[(t - 1) * 6 + 5], NWG);
                if (pool == 1) wg_wait(&iab[t], NWG);
            } else {
                wg_wait(&cntP[t * 6 + p - 1], NWG);
            }

            // batched activation (+ ring) loads, one vmcnt
            float rv[2][4];
            if (p == 0 && pool == 1) {
                #pragma unroll
                for (int q = 0; q < 2; ++q) {
                    const float* rp = ring + (t & 3) * BH + erow0 * 512 + (q ? col1 : col0);
                    #pragma unroll
                    for (int r = 0; r < 4; ++r) GLDF(rv[q][r], rp + r * 512);
                }
            }
            f16x8 a[16];
            #pragma unroll
            for (int ks = 0; ks < 16; ++ks) GLD16(a[ks], ap, ks * 64);
            VMWAIT();
            #pragma unroll
            for (int ks = 0; ks < 16; ++ks) TIE(a[ks]);
            if (p == 0 && pool == 1) {
                #pragma unroll
                for (int q = 0; q < 2; ++q)
                    #pragma unroll
                    for (int r = 0; r < 4; ++r) TIE(rv[q][r]);
            }

            f32x4 acc0 = {0.f,0.f,0.f,0.f}, acc1 = {0.f,0.f,0.f,0.f};
            #pragma unroll
            for (int ks = 0; ks < 16; ++ks) acc0 = MFMA(a[ks], w0[ks], acc0);
            #pragma unroll
            for (int ks = 0; ks < 16; ++ks) acc1 = MFMA(a[ks], *(const f16x8*)(bp1 + ks * 32), acc1);

            #pragma unroll
            for (int q = 0; q < 2; ++q) {
                const f32x4 acv = q ? acc1 : acc0;
                const int col = q ? col1 : col0;
                #pragma unroll
                for (int r = 0; r < 4; ++r) {
                    const int row = erow0 + r;
                    const float s = 2.f * sigf(acv[r] + mb[p][q]);
                    if ((p & 1) == 0) {
                        float xo;
                        if (p == 0) xo = (pool == 0) ? in_seq[(size_t)t * BH + row * 512 + col]
                                                     : rv[q][r];
                        else        xo = xreg[q][r];
                        const float xn = s * xo;
                        xreg[q][r] = xn;
                        st_h16(&x16[row * 512 + col], (_Float16)xn);
                    } else {
                        const float hn = s * hreg[q][r];
                        hreg[q][r] = hn;
                        st_h16(&hb[row * 512 + col], (_Float16)hn);
                    }
                }
            }
            wg_signal(&cntP[t * 6 + p]);
            if (p == 0 && pool == 1 && tid == 0)
                __hip_atomic_fetch_add(&iba[t], 1u, __ATOMIC_RELAXED, __HIP_MEMORY_SCOPE_AGENT);
        }

        // ---------------- LSTM gates ----------------
        wg_wait(&cntP[t * 6 + 4], NWG);
        if (pool == 0 && t >= 4) wg_wait(&iba[t - 4], NWG);   // ring slot free

        const _Float16* xa = x16 + arow * 512 + kof;
        const _Float16* ha = hb  + arow * 512 + kof;
        f16x8 ax[16], ah[16];
        #pragma unroll
        for (int ks = 0; ks < 16; ++ks) GLD16(ax[ks], xa, ks * 64);
        #pragma unroll
        for (int ks = 0; ks < 16; ++ks) GLD16(ah[ks], ha, ks * 64);
        VMWAIT();
        #pragma unroll
        for (int ks = 0; ks < 16; ++ks) { TIE(ax[ks]); TIE(ah[ks]); }

        #pragma unroll
        for (int q = 0; q < 2; ++q) {
            const size_t rg = (size_t)(256 * w + 64 * (b0 + 2 * q) + j) * 512 + kof;
            const _Float16* bi  = wihR + rg;
            const _Float16* bh_ = whhR + rg;
            f32x4 ac0 = {0.f,0.f,0.f,0.f}, ac1 = ac0, ac2 = ac0, ac3 = ac0;
            #pragma unroll
            for (int ks = 0; ks < 16; ++ks) {
                const int o = ks * 32;
                ac0 = MFMA(ax[ks], *(const f16x8*)(bi  +         o), ac0);
                ac0 = MFMA(ah[ks], *(const f16x8*)(bh_ +         o), ac0);
                ac1 = MFMA(ax[ks], *(const f16x8*)(bi  +  8192 + o), ac1);
                ac1 = MFMA(ah[ks], *(const f16x8*)(bh_ +  8192 + o), ac1);
                ac2 = MFMA(ax[ks], *(const f16x8*)(bi  + 16384 + o), ac2);
                ac2 = MFMA(ah[ks], *(const f16x8*)(bh_ + 16384 + o), ac2);
                ac3 = MFMA(ax[ks], *(const f16x8*)(bi  + 24576 + o), ac3);
                ac3 = MFMA(ah[ks], *(const f16x8*)(bh_ + 24576 + o), ac3);
            }
            const int hc = q ? col1 : col0;
            #pragma unroll
            for (int r = 0; r < 4; ++r) {
                const int row = erow0 + r;
                const float ig = sigf (ac0[r] + gb[q][0]);
                const float fg = sigf (ac1[r] + gb[q][1]);
                const float gg = tanhf(ac2[r] + gb[q][2]);
                const float og = sigf (ac3[r] + gb[q][3]);
                const float cn = fg * creg[q][r] + ig * gg;
                creg[q][r] = cn;
                const float hn = og * tanhf(cn);
                hreg[q][r] = hn;
                st_h16(&ho[row * 512 + hc], (_Float16)hn);
                if (pool == 0) st_f32cc(&ring[(t & 3) * BH + row * 512 + hc], hn);
                else __builtin_nontemporal_store(hn, &out[(size_t)t * BH + row * 512 + hc]);
                if (t == SEQ - 1) {
                    __builtin_nontemporal_store(hn, &out[OUT_H + pool * BH + row * 512 + hc]);
                    __builtin_nontemporal_store(cn, &out[OUT_C + pool * BH + row * 512 + hc]);
                }
            }
        }
        wg_signal(&cntP[t * 6 + 5]);
        if (pool == 0 && tid == 0)
            __hip_atomic_fetch_add(&iab[t], 1u, __ATOMIC_RELAXED, __HIP_MEMORY_SCOPE_AGENT);
    }
}

// ---------------- host launch ----------------
extern "C" void kernel_launch(void* const* d_in, const int* in_sizes, int n_in,
                              void* d_out, int out_size, void* d_ws, size_t ws_size,
                              hipStream_t stream) {
    const float* in_seq  = (const float*)d_in[0];
    const float* l1_mogW = (const float*)d_in[1];
    const float* l1_mogb = (const float*)d_in[2];
    const float* l1_Wih  = (const float*)d_in[3];
    const float* l1_Whh  = (const float*)d_in[4];
    const float* l1_bih  = (const float*)d_in[5];
    const float* l1_bhh  = (const float*)d_in[6];
    const float* l2_mogW = (const float*)d_in[7];
    const float* l2_mogb = (const float*)d_in[8];
    const float* l2_Wih  = (const float*)d_in[9];
    const float* l2_Whh  = (const float*)d_in[10];
    const float* l2_bih  = (const float*)d_in[11];
    const float* l2_bhh  = (const float*)d_in[12];

    hipMemsetAsync(d_ws, 0, ZERO_PREFIX, stream);

    prologue_convert<<<256, 256, 0, stream>>>(l1_mogW, l1_Wih, l1_Whh,
                                              l2_mogW, l2_Wih, l2_Whh, (char*)d_ws);

    moglstm_persist<<<16, NTHR, 0, stream>>>(in_seq, l1_mogb, l2_mogb,
                                             l1_bih, l1_bhh, l2_bih, l2_bhh,
                                             (float*)d_out, (char*)d_ws);
}